// Round 13
// baseline (168.089 us; speedup 1.0000x reference)
//
#include <hip/hip_runtime.h>

#define HW    3136
#define CIN   64
#define MIDC  32
#define HEADS 8
#define DTOT  256
#define COUTC 64
#define WDIM  56
#define QT    32
#define L2E   1.4426950408889634f

typedef unsigned int uint_t;
typedef _Float16 f16;
typedef __attribute__((ext_vector_type(8))) _Float16 half8;
typedef __attribute__((ext_vector_type(4))) _Float16 f16x4;
typedef __attribute__((ext_vector_type(2))) __fp16  fp16x2;
typedef __attribute__((ext_vector_type(4))) float f32x4;

union HU { fp16x2 h; uint_t u; };
__device__ __forceinline__ uint_t pkh(float a, float b) {
    HU u; u.h = __builtin_amdgcn_cvt_pkrtz(a, b); return u.u;
}
union PU { uint_t u[4]; half8 h; };          // 4 packed f16-pairs -> B-frag
union VU { struct { f16x4 lo, hi; } p; half8 h; };   // 2x b64 -> A-frag

// ---------------- Kernel 1: fused QKV conv + layout (fp32 in -> f16 ws) ------
__global__ __launch_bounds__(256) void qkv_fused_kernel(
    const float* __restrict__ x,
    const float* __restrict__ Wq, const float* __restrict__ bq,
    const float* __restrict__ Wk, const float* __restrict__ bk,
    const float* __restrict__ Wv, const float* __restrict__ bv,
    f16* __restrict__ qh, f16* __restrict__ kh, f16* __restrict__ vh)
{
    __shared__ float xs[64][36];
    __shared__ float Wlq[64][34];
    __shared__ float Wlk[64][34];
    __shared__ float Wlv[64][34];

    const int tid = threadIdx.x;
    const int h   = blockIdx.y;
    const int P0  = blockIdx.x * 32;

    {   int c = tid >> 2, g = tid & 3;
        const float* src = &x[(size_t)c * HW + P0 + g * 8];
        float4 v0 = *(const float4*)src;
        float4 v1 = *(const float4*)(src + 4);
        *(float4*)&xs[c][g * 8]     = v0;
        *(float4*)&xs[c][g * 8 + 4] = v1;
    }
    {   int m = tid >> 3, c8 = (tid & 7) * 8;
        size_t row = (size_t)(m * HEADS + h) * CIN + c8;
        float4 a0 = *(const float4*)&Wq[row], a1 = *(const float4*)&Wq[row + 4];
        float4 b0 = *(const float4*)&Wk[row], b1 = *(const float4*)&Wk[row + 4];
        float4 c0 = *(const float4*)&Wv[row], c1 = *(const float4*)&Wv[row + 4];
        #pragma unroll
        for (int i = 0; i < 4; ++i) {
            Wlq[c8 + i][m]     = ((const float*)&a0)[i];
            Wlq[c8 + 4 + i][m] = ((const float*)&a1)[i];
            Wlk[c8 + i][m]     = ((const float*)&b0)[i];
            Wlk[c8 + 4 + i][m] = ((const float*)&b1)[i];
            Wlv[c8 + i][m]     = ((const float*)&c0)[i];
            Wlv[c8 + 4 + i][m] = ((const float*)&c1)[i];
        }
    }
    __syncthreads();

    const int a  = tid & 15, pg = tid >> 4;
    const int m0 = a * 2,    p0 = pg * 2;
    const int d0 = m0 * HEADS + h, d1 = d0 + HEADS;

    float q00 = bq[d0], q01 = q00, q10 = bq[d1], q11 = q10;
    float k00 = bk[d0], k01 = k00, k10 = bk[d1], k11 = k10;
    float v00 = bv[d0], v01 = v00, v10 = bv[d1], v11 = v10;

    #pragma unroll 8
    for (int c = 0; c < CIN; ++c) {
        float x0 = xs[c][p0], x1 = xs[c][p0 + 1];
        float wq0 = Wlq[c][m0], wq1 = Wlq[c][m0 + 1];
        float wk0 = Wlk[c][m0], wk1 = Wlk[c][m0 + 1];
        float wv0 = Wlv[c][m0], wv1 = Wlv[c][m0 + 1];
        q00 += wq0 * x0; q01 += wq0 * x1; q10 += wq1 * x0; q11 += wq1 * x1;
        k00 += wk0 * x0; k01 += wk0 * x1; k10 += wk1 * x0; k11 += wk1 * x1;
        v00 += wv0 * x0; v01 += wv0 * x1; v10 += wv1 * x0; v11 += wv1 * x1;
    }

    size_t qk0 = (size_t)h * HW * MIDC + (size_t)(P0 + p0) * MIDC + m0;
    *(uint_t*)&qh[qk0]        = pkh(q00, q10);
    *(uint_t*)&qh[qk0 + MIDC] = pkh(q01, q11);
    *(uint_t*)&kh[qk0]        = pkh(k00, k10);
    *(uint_t*)&kh[qk0 + MIDC] = pkh(k01, k11);
    size_t vb0 = (size_t)(h * MIDC + m0) * HW + P0 + p0;
    *(uint_t*)&vh[vb0]      = pkh(v00, v01);
    *(uint_t*)&vh[vb0 + HW] = pkh(v10, v11);
}

// ---------------- Kernel 2: MFMA flash attention, QT=32, register-resident P -
// grid (98, 8), 4 waves, K-split by wave; wave 0 does tile 48.
// P stays in registers: PV uses k-permutation pi(grp*8+j) = 32c + (j>=4?16:0)
// + grp*4 + (j&3) applied to BOTH V (A-frag load address) and P (B-frag from
// the lane's own packed exps) — permutation cancels in the MFMA k-sum.
// NOTE: (256,3) — (256,4) caps regs at 128/lane -> fragment spill (round 10:
// 400 MB HBM scratch traffic). Do not raise.
__global__ __launch_bounds__(256, 3) void attn_kernel(
    const f16* __restrict__ qh, const f16* __restrict__ kh,
    const f16* __restrict__ vh,
    const float* __restrict__ rowt, const float* __restrict__ colt,
    f16* __restrict__ obf)
{
    __shared__ f16   Qs[QT][MIDC];                  // 2 KB
    __shared__ float Rb[QT][57];                    // 7.3 KB
    __shared__ float Cb[QT][60];                    // 7.7 KB (16B-aligned rows)
    __shared__ __align__(16) float pool[4*32*36 + 128];   // merge bufs only

    const int tid   = threadIdx.x;
    const int wave  = tid >> 6, lane = tid & 63;
    const int h     = blockIdx.y;
    const int qbase = blockIdx.x * QT;
    const float c1  = 0.125f * L2E;

    const f16* Qh = qh + (size_t)h * HW * MIDC;
    const f16* Kh = kh + (size_t)h * HW * MIDC;
    const f16* Vh = vh + (size_t)h * MIDC * HW;

    if (tid < 128) {
        int r = tid >> 2, c = (tid & 3) * 8;
        *(uint4*)&Qs[r][c] = *(const uint4*)&Qh[(size_t)(qbase + r) * MIDC + c];
    }
    __syncthreads();

    {   // bias tables: thread owns one q, 7 kp entries; Q-row via 4 b128 reads
        int q = tid >> 3, sub = tid & 7;
        int qg = qbase + q, qi = qg / WDIM, qj = qg % WDIM;
        half8 qr0 = *(const half8*)&Qs[q][0];
        half8 qr1 = *(const half8*)&Qs[q][8];
        half8 qr2 = *(const half8*)&Qs[q][16];
        half8 qr3 = *(const half8*)&Qs[q][24];
        for (int kp = sub; kp < WDIM; kp += 8) {
            const float* rt = &rowt[(kp - qi + WDIM - 1) * 16];
            const float* ct = &colt[(kp - qj + WDIM - 1) * 16];
            float s = 0.f, s2 = 0.f;
            #pragma unroll
            for (int c = 0; c < 8; ++c) {
                s  += (float)qr0[c] * rt[c] + (float)qr1[c] * rt[8 + c];
                s2 += (float)qr2[c] * ct[c] + (float)qr3[c] * ct[8 + c];
            }
            Rb[q][kp] = s * c1;
            Cb[q][kp] = s2 * c1;
        }
    }
    __syncthreads();

    const int qL  = lane & 15;
    const int grp = lane >> 4;
    half8 qfrag[2];
    qfrag[0] = *(const half8*)&Qs[qL][grp * 8];
    qfrag[1] = *(const half8*)&Qs[16 + qL][grp * 8];

    float lacc[2] = {0.f, 0.f};
    f32x4 o[2][2];
    #pragma unroll
    for (int i = 0; i < 2; ++i) { o[i][0] = (f32x4){0,0,0,0}; o[i][1] = (f32x4){0,0,0,0}; }

    int ki_s[8], kj_s[8];
    #pragma unroll
    for (int s = 0; s < 8; ++s) {
        int key0 = wave * 128 + s * 16 + grp * 4;
        ki_s[s] = key0 / WDIM;
        kj_s[s] = key0 % WDIM;                       // multiple of 4, <= 52
    }

    for (int j6 = 0; j6 < 6; ++j6) {
        const int base = 512 * j6 + 128 * wave;

        half8 kfr[8];
        #pragma unroll
        for (int s = 0; s < 8; ++s)
            kfr[s] = *(const half8*)&Kh[(size_t)(base + s*16 + qL) * MIDC + grp*8];
        // V A-frags with pi-permuted k: two b64 per (ch, chunk)
        VU vfr[2][4];
        #pragma unroll
        for (int ch = 0; ch < 2; ++ch)
            #pragma unroll
            for (int c = 0; c < 4; ++c) {
                const f16* vsrc = &Vh[(size_t)(ch*16 + qL) * HW + base + c*32 + grp*4];
                vfr[ch][c].p.lo = *(const f16x4*)vsrc;
                vfr[ch][c].p.hi = *(const f16x4*)(vsrc + 16);
            }

        #pragma unroll
        for (int hf = 0; hf < 2; ++hf) {
            const int qrow = hf * 16 + qL;
            f32x4 sc[8];
            #pragma unroll
            for (int s = 0; s < 8; ++s) {
                f32x4 z = {0.f,0.f,0.f,0.f};
                sc[s] = __builtin_amdgcn_mfma_f32_16x16x32_f16(kfr[s], qfrag[hf], z, 0,0,0);
            }
            #pragma unroll
            for (int c = 0; c < 4; ++c) {
                PU pu;
                #pragma unroll
                for (int t = 0; t < 2; ++t) {        // subtiles 2c, 2c+1
                    const int s = 2*c + t;
                    float rb = Rb[qrow][ki_s[s]];
                    float4 cbv = *(const float4*)&Cb[qrow][kj_s[s]];
                    float e0 = __builtin_amdgcn_exp2f(fmaf(sc[s][0], c1, rb + cbv.x));
                    float e1 = __builtin_amdgcn_exp2f(fmaf(sc[s][1], c1, rb + cbv.y));
                    float e2 = __builtin_amdgcn_exp2f(fmaf(sc[s][2], c1, rb + cbv.z));
                    float e3 = __builtin_amdgcn_exp2f(fmaf(sc[s][3], c1, rb + cbv.w));
                    lacc[hf] += (e0 + e1) + (e2 + e3);
                    pu.u[2*t]   = pkh(e0, e1);
                    pu.u[2*t+1] = pkh(e2, e3);
                }
                o[hf][0] = __builtin_amdgcn_mfma_f32_16x16x32_f16(vfr[0][c].h, pu.h, o[hf][0], 0,0,0);
                o[hf][1] = __builtin_amdgcn_mfma_f32_16x16x32_f16(vfr[1][c].h, pu.h, o[hf][1], 0,0,0);
            }
        }

        #pragma unroll
        for (int s = 0; s < 8; ++s) {                // advance keys by 512
            kj_s[s] += 8;
            if (kj_s[s] >= WDIM) { kj_s[s] -= WDIM; ki_s[s] += 10; }
            else                 { ki_s[s] += 9; }
        }
    }

    if (wave == 0) {       // tile 48: keys 3072..3135 (2 chunks)
        const int base = 3072;
        half8 kfr[4];
        #pragma unroll
        for (int s = 0; s < 4; ++s)
            kfr[s] = *(const half8*)&Kh[(size_t)(base + s*16 + qL) * MIDC + grp*8];
        VU vfr[2][2];
        #pragma unroll
        for (int ch = 0; ch < 2; ++ch)
            #pragma unroll
            for (int c = 0; c < 2; ++c) {
                const f16* vsrc = &Vh[(size_t)(ch*16 + qL) * HW + base + c*32 + grp*4];
                vfr[ch][c].p.lo = *(const f16x4*)vsrc;
                vfr[ch][c].p.hi = *(const f16x4*)(vsrc + 16);
            }
        #pragma unroll
        for (int hf = 0; hf < 2; ++hf) {
            const int qrow = hf * 16 + qL;
            f32x4 sc[4];
            #pragma unroll
            for (int s = 0; s < 4; ++s) {
                f32x4 z = {0.f,0.f,0.f,0.f};
                sc[s] = __builtin_amdgcn_mfma_f32_16x16x32_f16(kfr[s], qfrag[hf], z, 0,0,0);
            }
            #pragma unroll
            for (int c = 0; c < 2; ++c) {
                PU pu;
                #pragma unroll
                for (int t = 0; t < 2; ++t) {
                    const int s = 2*c + t;
                    int key0 = base + s * 16 + grp * 4;
                    int ki = key0 / WDIM, kj = key0 % WDIM;
                    float rb = Rb[qrow][ki];
                    float4 cbv = *(const float4*)&Cb[qrow][kj];
                    float e0 = __builtin_amdgcn_exp2f(fmaf(sc[s][0], c1, rb + cbv.x));
                    float e1 = __builtin_amdgcn_exp2f(fmaf(sc[s][1], c1, rb + cbv.y));
                    float e2 = __builtin_amdgcn_exp2f(fmaf(sc[s][2], c1, rb + cbv.z));
                    float e3 = __builtin_amdgcn_exp2f(fmaf(sc[s][3], c1, rb + cbv.w));
                    lacc[hf] += (e0 + e1) + (e2 + e3);
                    pu.u[2*t]   = pkh(e0, e1);
                    pu.u[2*t+1] = pkh(e2, e3);
                }
                o[hf][0] = __builtin_amdgcn_mfma_f32_16x16x32_f16(vfr[0][c].h, pu.h, o[hf][0], 0,0,0);
                o[hf][1] = __builtin_amdgcn_mfma_f32_16x16x32_f16(vfr[1][c].h, pu.h, o[hf][1], 0,0,0);
            }
        }
    }

    #pragma unroll
    for (int hf = 0; hf < 2; ++hf) {
        lacc[hf] += __shfl_xor(lacc[hf], 16);
        lacc[hf] += __shfl_xor(lacc[hf], 32);
    }

    // merge 4 waves (plain sums), normalize, write f16 obf[pos][cc=h*32+m]
    __syncthreads();
    float* MOb = pool;                           // [4][32][36]
    float* Ll  = MOb + 4 * 32 * 36;              // [4][32]
    #pragma unroll
    for (int hf = 0; hf < 2; ++hf) {
        int row = wave * 32 + hf * 16 + qL;
        *(f32x4*)&MOb[row * 36 + grp * 4]      = o[hf][0];
        *(f32x4*)&MOb[row * 36 + 16 + grp * 4] = o[hf][1];
        if (grp == 0) Ll[row] = lacc[hf];
    }
    __syncthreads();

    {
        int q = tid & 31, cseg = tid >> 5;       // cseg 0..7 -> 4 channels each
        float l = (Ll[q] + Ll[32+q]) + (Ll[64+q] + Ll[96+q]);
        float invl = 1.f / l;
        int qg = qbase + q;
        float a0 = 0.f, a1 = 0.f, a2 = 0.f, a3 = 0.f;
        #pragma unroll
        for (int w = 0; w < 4; ++w) {
            const float* r = &MOb[(w*32 + q) * 36 + cseg * 4];
            a0 += r[0]; a1 += r[1]; a2 += r[2]; a3 += r[3];
        }
        uint2 pk;
        pk.x = pkh(a0 * invl, a1 * invl);
        pk.y = pkh(a2 * invl, a3 * invl);
        *(uint2*)&obf[(size_t)qg * DTOT + h * MIDC + cseg * 4] = pk;
    }
}

// ---------------- Kernel 3: output 1x1 conv via MFMA, LDS-staged Wo ----------
__global__ __launch_bounds__(256) void outproj_kernel(
    const f16* __restrict__ obf, const float* __restrict__ Wo,
    const float* __restrict__ bo, float* __restrict__ out)
{
    __shared__ f16  WoL[64][264];                // [d][cc] f16, pad 264 (33 KB)
    __shared__ float bol[64];

    const int tid = threadIdx.x;
    {
        int d = tid >> 2, part = tid & 3;
        const float* wr = &Wo[(size_t)d * DTOT];
        #pragma unroll
        for (int i = 0; i < 32; ++i) {
            int cc = part * 64 + i * 2;
            int h0 = cc >> 5, m0 = cc & 31;
            float w0 = wr[m0 * 8 + h0];
            float w1 = wr[(m0 + 1) * 8 + h0];
            *(uint_t*)&WoL[d][cc] = pkh(w0, w1);
        }
        if (tid < 64) bol[tid] = bo[tid];
    }
    __syncthreads();

    const int wave = tid >> 6, lane = tid & 63;
    const int qL = lane & 15, grp = lane >> 4;
    const int p = blockIdx.x * 64 + wave * 16 + qL;

    f32x4 acc[4];
    #pragma unroll
    for (int mt = 0; mt < 4; ++mt) acc[mt] = (f32x4){0,0,0,0};

    #pragma unroll
    for (int ks = 0; ks < 8; ++ks) {
        half8 bf = *(const half8*)&obf[(size_t)p * DTOT + ks * 32 + grp * 8];
        #pragma unroll
        for (int mt = 0; mt < 4; ++mt) {
            half8 af = *(const half8*)&WoL[mt * 16 + qL][ks * 32 + grp * 8];
            acc[mt] = __builtin_amdgcn_mfma_f32_16x16x32_f16(af, bf, acc[mt], 0, 0, 0);
        }
    }

    #pragma unroll
    for (int mt = 0; mt < 4; ++mt)
        #pragma unroll
        for (int r = 0; r < 4; ++r) {
            int d = mt * 16 + grp * 4 + r;
            out[(size_t)d * HW + p] = acc[mt][r] + bol[d];
        }
}

extern "C" void kernel_launch(void* const* d_in, const int* in_sizes, int n_in,
                              void* d_out, int out_size, void* d_ws, size_t ws_size,
                              hipStream_t stream)
{
    const float* x    = (const float*)d_in[0];
    const float* Wq   = (const float*)d_in[1];
    const float* bq   = (const float*)d_in[2];
    const float* Wk   = (const float*)d_in[3];
    const float* bk   = (const float*)d_in[4];
    const float* Wv   = (const float*)d_in[5];
    const float* bv   = (const float*)d_in[6];
    const float* Wo   = (const float*)d_in[7];
    const float* bo   = (const float*)d_in[8];
    const float* rowt = (const float*)d_in[9];
    const float* colt = (const float*)d_in[10];
    float* out = (float*)d_out;

    const size_t N = (size_t)DTOT * HW;
    f16* qh  = (f16*)d_ws;                       // [h][pos][32]
    f16* kh  = qh + N;
    f16* vh  = kh + N;                           // [h*32+m][pos]
    f16* obf = vh + N;                           // [pos][256] f16 normalized O

    qkv_fused_kernel<<<dim3(HW / 32, HEADS), 256, 0, stream>>>(
        x, Wq, bq, Wk, bk, Wv, bv, qh, kh, vh);
    attn_kernel<<<dim3(HW / QT, HEADS), 256, 0, stream>>>(
        qh, kh, vh, rowt, colt, obf);
    outproj_kernel<<<dim3(HW / 64), 256, 0, stream>>>(obf, Wo, bo, out);
}

// Round 14
// 150.265 us; speedup vs baseline: 1.1186x; 1.1186x over previous
//
#include <hip/hip_runtime.h>

#define HW    3136
#define CIN   64
#define MIDC  32
#define HEADS 8
#define DTOT  256
#define COUTC 64
#define WDIM  56
#define QT    32
#define L2E   1.4426950408889634f

typedef unsigned int uint_t;
typedef _Float16 f16;
typedef __attribute__((ext_vector_type(8))) _Float16 half8;
typedef __attribute__((ext_vector_type(2))) __fp16  fp16x2;
typedef __attribute__((ext_vector_type(4))) float f32x4;

union HU { fp16x2 h; uint_t u; };
__device__ __forceinline__ uint_t pkh(float a, float b) {
    HU u; u.h = __builtin_amdgcn_cvt_pkrtz(a, b); return u.u;
}

// ---------------- Kernel 1: fused QKV conv + layout (fp32 in -> f16 ws) ------
__global__ __launch_bounds__(256) void qkv_fused_kernel(
    const float* __restrict__ x,
    const float* __restrict__ Wq, const float* __restrict__ bq,
    const float* __restrict__ Wk, const float* __restrict__ bk,
    const float* __restrict__ Wv, const float* __restrict__ bv,
    f16* __restrict__ qh, f16* __restrict__ kh, f16* __restrict__ vh)
{
    __shared__ float xs[64][36];
    __shared__ float Wlq[64][34];
    __shared__ float Wlk[64][34];
    __shared__ float Wlv[64][34];

    const int tid = threadIdx.x;
    const int h   = blockIdx.y;
    const int P0  = blockIdx.x * 32;

    {   int c = tid >> 2, g = tid & 3;
        const float* src = &x[(size_t)c * HW + P0 + g * 8];
        float4 v0 = *(const float4*)src;
        float4 v1 = *(const float4*)(src + 4);
        *(float4*)&xs[c][g * 8]     = v0;
        *(float4*)&xs[c][g * 8 + 4] = v1;
    }
    {   int m = tid >> 3, c8 = (tid & 7) * 8;
        size_t row = (size_t)(m * HEADS + h) * CIN + c8;
        float4 a0 = *(const float4*)&Wq[row], a1 = *(const float4*)&Wq[row + 4];
        float4 b0 = *(const float4*)&Wk[row], b1 = *(const float4*)&Wk[row + 4];
        float4 c0 = *(const float4*)&Wv[row], c1 = *(const float4*)&Wv[row + 4];
        #pragma unroll
        for (int i = 0; i < 4; ++i) {
            Wlq[c8 + i][m]     = ((const float*)&a0)[i];
            Wlq[c8 + 4 + i][m] = ((const float*)&a1)[i];
            Wlk[c8 + i][m]     = ((const float*)&b0)[i];
            Wlk[c8 + 4 + i][m] = ((const float*)&b1)[i];
            Wlv[c8 + i][m]     = ((const float*)&c0)[i];
            Wlv[c8 + 4 + i][m] = ((const float*)&c1)[i];
        }
    }
    __syncthreads();

    const int a  = tid & 15, pg = tid >> 4;
    const int m0 = a * 2,    p0 = pg * 2;
    const int d0 = m0 * HEADS + h, d1 = d0 + HEADS;

    float q00 = bq[d0], q01 = q00, q10 = bq[d1], q11 = q10;
    float k00 = bk[d0], k01 = k00, k10 = bk[d1], k11 = k10;
    float v00 = bv[d0], v01 = v00, v10 = bv[d1], v11 = v10;

    #pragma unroll 8
    for (int c = 0; c < CIN; ++c) {
        float x0 = xs[c][p0], x1 = xs[c][p0 + 1];
        float wq0 = Wlq[c][m0], wq1 = Wlq[c][m0 + 1];
        float wk0 = Wlk[c][m0], wk1 = Wlk[c][m0 + 1];
        float wv0 = Wlv[c][m0], wv1 = Wlv[c][m0 + 1];
        q00 += wq0 * x0; q01 += wq0 * x1; q10 += wq1 * x0; q11 += wq1 * x1;
        k00 += wk0 * x0; k01 += wk0 * x1; k10 += wk1 * x0; k11 += wk1 * x1;
        v00 += wv0 * x0; v01 += wv0 * x1; v10 += wv1 * x0; v11 += wv1 * x1;
    }

    size_t qk0 = (size_t)h * HW * MIDC + (size_t)(P0 + p0) * MIDC + m0;
    *(uint_t*)&qh[qk0]        = pkh(q00, q10);
    *(uint_t*)&qh[qk0 + MIDC] = pkh(q01, q11);
    *(uint_t*)&kh[qk0]        = pkh(k00, k10);
    *(uint_t*)&kh[qk0 + MIDC] = pkh(k01, k11);
    size_t vb0 = (size_t)(h * MIDC + m0) * HW + P0 + p0;
    *(uint_t*)&vh[vb0]      = pkh(v00, v01);
    *(uint_t*)&vh[vb0 + HW] = pkh(v10, v11);
}

// ---------------- Kernel 2: MFMA flash attention, QT=32 (round-12 config) ----
// grid (98, 8), 4 waves, K-split by wave; wave 0 does tile 48.
// Epilogue: normalized O -> f16 obf[pos][cc], cc = h*32 + m.
// NOTE: (256,3) — (256,4) caps regs at 128/lane -> kfr/vfr spill (round 10:
// 400 MB HBM scratch traffic). Do not raise.
// NOTE: keep V loads as single b128 per (ch,chunk) — splitting them into 2x b64
// (round 13 register-P variant) doubled VMEM ops on V's scattered pattern and
// cost +15 us; the P LDS round-trip here is latency-hidden by the 2-hf overlap.
__global__ __launch_bounds__(256, 3) void attn_kernel(
    const f16* __restrict__ qh, const f16* __restrict__ kh,
    const f16* __restrict__ vh,
    const float* __restrict__ rowt, const float* __restrict__ colt,
    f16* __restrict__ obf)
{
    __shared__ f16   Qs[QT][MIDC];                  // 2 KB
    __shared__ float Rb[QT][57];                    // 7.3 KB
    __shared__ float Cb[QT][60];                    // 7.7 KB (16B-aligned rows)
    __shared__ __align__(16) char pool[18944];      // P[4][16][136] f16; merge alias
    f16* PlBase = (f16*)pool;

    const int tid   = threadIdx.x;
    const int wave  = tid >> 6, lane = tid & 63;
    const int h     = blockIdx.y;
    const int qbase = blockIdx.x * QT;
    const float c1  = 0.125f * L2E;

    const f16* Qh = qh + (size_t)h * HW * MIDC;
    const f16* Kh = kh + (size_t)h * HW * MIDC;
    const f16* Vh = vh + (size_t)h * MIDC * HW;

    if (tid < 128) {
        int r = tid >> 2, c = (tid & 3) * 8;
        *(uint4*)&Qs[r][c] = *(const uint4*)&Qh[(size_t)(qbase + r) * MIDC + c];
    }
    __syncthreads();

    {   // bias tables: thread owns one q, 7 kp entries; Q-row via 4 b128 reads
        int q = tid >> 3, sub = tid & 7;
        int qg = qbase + q, qi = qg / WDIM, qj = qg % WDIM;
        half8 qr0 = *(const half8*)&Qs[q][0];
        half8 qr1 = *(const half8*)&Qs[q][8];
        half8 qr2 = *(const half8*)&Qs[q][16];
        half8 qr3 = *(const half8*)&Qs[q][24];
        for (int kp = sub; kp < WDIM; kp += 8) {
            const float* rt = &rowt[(kp - qi + WDIM - 1) * 16];
            const float* ct = &colt[(kp - qj + WDIM - 1) * 16];
            float s = 0.f, s2 = 0.f;
            #pragma unroll
            for (int c = 0; c < 8; ++c) {
                s  += (float)qr0[c] * rt[c] + (float)qr1[c] * rt[8 + c];
                s2 += (float)qr2[c] * ct[c] + (float)qr3[c] * ct[8 + c];
            }
            Rb[q][kp] = s * c1;
            Cb[q][kp] = s2 * c1;
        }
    }
    __syncthreads();

    const int qL  = lane & 15;
    const int grp = lane >> 4;
    half8 qfrag[2];
    qfrag[0] = *(const half8*)&Qs[qL][grp * 8];
    qfrag[1] = *(const half8*)&Qs[16 + qL][grp * 8];

    float lacc[2] = {0.f, 0.f};
    f32x4 o[2][2];
    #pragma unroll
    for (int i = 0; i < 2; ++i) { o[i][0] = (f32x4){0,0,0,0}; o[i][1] = (f32x4){0,0,0,0}; }

    int ki_s[8], kj_s[8];
    #pragma unroll
    for (int s = 0; s < 8; ++s) {
        int key0 = wave * 128 + s * 16 + grp * 4;
        ki_s[s] = key0 / WDIM;
        kj_s[s] = key0 % WDIM;                       // multiple of 4, <= 52
    }

    f16* Pw = PlBase + wave * (16 * 136);

    for (int j = 0; j < 6; ++j) {
        const int base = 512 * j + 128 * wave;

        half8 kfr[8];
        #pragma unroll
        for (int s = 0; s < 8; ++s)
            kfr[s] = *(const half8*)&Kh[(size_t)(base + s*16 + qL) * MIDC + grp*8];
        half8 vfr[2][4];
        #pragma unroll
        for (int ch = 0; ch < 2; ++ch)
            #pragma unroll
            for (int kf2 = 0; kf2 < 4; ++kf2)
                vfr[ch][kf2] = *(const half8*)
                    &Vh[(size_t)(ch*16 + qL) * HW + base + kf2*32 + grp*8];

        #pragma unroll
        for (int hf = 0; hf < 2; ++hf) {
            const int qrow = hf * 16 + qL;
            f32x4 sc[8];
            #pragma unroll
            for (int s = 0; s < 8; ++s) {
                f32x4 z = {0.f,0.f,0.f,0.f};
                sc[s] = __builtin_amdgcn_mfma_f32_16x16x32_f16(kfr[s], qfrag[hf], z, 0,0,0);
            }
            #pragma unroll
            for (int s = 0; s < 8; ++s) {
                float rb = Rb[qrow][ki_s[s]];
                float4 cbv = *(const float4*)&Cb[qrow][kj_s[s]];
                float e0 = __builtin_amdgcn_exp2f(fmaf(sc[s][0], c1, rb + cbv.x));
                float e1 = __builtin_amdgcn_exp2f(fmaf(sc[s][1], c1, rb + cbv.y));
                float e2 = __builtin_amdgcn_exp2f(fmaf(sc[s][2], c1, rb + cbv.z));
                float e3 = __builtin_amdgcn_exp2f(fmaf(sc[s][3], c1, rb + cbv.w));
                lacc[hf] += (e0 + e1) + (e2 + e3);
                uint2 w2; w2.x = pkh(e0, e1); w2.y = pkh(e2, e3);
                *(uint2*)&Pw[qL * 136 + s * 16 + grp * 4] = w2;
            }
            #pragma unroll
            for (int kf2 = 0; kf2 < 4; ++kf2) {
                half8 pf = *(const half8*)&Pw[qL * 136 + kf2 * 32 + grp * 8];
                o[hf][0] = __builtin_amdgcn_mfma_f32_16x16x32_f16(vfr[0][kf2], pf, o[hf][0], 0,0,0);
                o[hf][1] = __builtin_amdgcn_mfma_f32_16x16x32_f16(vfr[1][kf2], pf, o[hf][1], 0,0,0);
            }
        }

        #pragma unroll
        for (int s = 0; s < 8; ++s) {                // advance keys by 512
            kj_s[s] += 8;
            if (kj_s[s] >= WDIM) { kj_s[s] -= WDIM; ki_s[s] += 10; }
            else                 { ki_s[s] += 9; }
        }
    }

    if (wave == 0) {       // tile 48: keys 3072..3135
        const int base = 3072;
        half8 kfr[4];
        #pragma unroll
        for (int s = 0; s < 4; ++s)
            kfr[s] = *(const half8*)&Kh[(size_t)(base + s*16 + qL) * MIDC + grp*8];
        half8 vfr[2][2];
        #pragma unroll
        for (int ch = 0; ch < 2; ++ch)
            #pragma unroll
            for (int kf2 = 0; kf2 < 2; ++kf2)
                vfr[ch][kf2] = *(const half8*)
                    &Vh[(size_t)(ch*16 + qL) * HW + base + kf2*32 + grp*8];
        #pragma unroll
        for (int hf = 0; hf < 2; ++hf) {
            const int qrow = hf * 16 + qL;
            f32x4 sc[4];
            #pragma unroll
            for (int s = 0; s < 4; ++s) {
                f32x4 z = {0.f,0.f,0.f,0.f};
                sc[s] = __builtin_amdgcn_mfma_f32_16x16x32_f16(kfr[s], qfrag[hf], z, 0,0,0);
            }
            #pragma unroll
            for (int s = 0; s < 4; ++s) {
                int key0 = base + s * 16 + grp * 4;
                int ki = key0 / WDIM, kj = key0 % WDIM;
                float rb = Rb[qrow][ki];
                float4 cbv = *(const float4*)&Cb[qrow][kj];
                float e0 = __builtin_amdgcn_exp2f(fmaf(sc[s][0], c1, rb + cbv.x));
                float e1 = __builtin_amdgcn_exp2f(fmaf(sc[s][1], c1, rb + cbv.y));
                float e2 = __builtin_amdgcn_exp2f(fmaf(sc[s][2], c1, rb + cbv.z));
                float e3 = __builtin_amdgcn_exp2f(fmaf(sc[s][3], c1, rb + cbv.w));
                lacc[hf] += (e0 + e1) + (e2 + e3);
                uint2 w2; w2.x = pkh(e0, e1); w2.y = pkh(e2, e3);
                *(uint2*)&Pw[qL * 136 + s * 16 + grp * 4] = w2;
            }
            #pragma unroll
            for (int kf2 = 0; kf2 < 2; ++kf2) {
                half8 pf = *(const half8*)&Pw[qL * 136 + kf2 * 32 + grp * 8];
                o[hf][0] = __builtin_amdgcn_mfma_f32_16x16x32_f16(vfr[0][kf2], pf, o[hf][0], 0,0,0);
                o[hf][1] = __builtin_amdgcn_mfma_f32_16x16x32_f16(vfr[1][kf2], pf, o[hf][1], 0,0,0);
            }
        }
    }

    #pragma unroll
    for (int hf = 0; hf < 2; ++hf) {
        lacc[hf] += __shfl_xor(lacc[hf], 16);
        lacc[hf] += __shfl_xor(lacc[hf], 32);
    }

    // merge 4 waves (plain sums), normalize, write f16 obf[pos][cc=h*32+m]
    __syncthreads();
    float* MOb = (float*)pool;                   // [4][32][36]
    float* Ll  = MOb + 4 * 32 * 36;              // [4][32]
    #pragma unroll
    for (int hf = 0; hf < 2; ++hf) {
        int row = wave * 32 + hf * 16 + qL;
        *(f32x4*)&MOb[row * 36 + grp * 4]      = o[hf][0];
        *(f32x4*)&MOb[row * 36 + 16 + grp * 4] = o[hf][1];
        if (grp == 0) Ll[row] = lacc[hf];
    }
    __syncthreads();

    {
        int q = tid & 31, cseg = tid >> 5;       // cseg 0..7 -> 4 channels each
        float l = (Ll[q] + Ll[32+q]) + (Ll[64+q] + Ll[96+q]);
        float invl = 1.f / l;
        int qg = qbase + q;
        float a0 = 0.f, a1 = 0.f, a2 = 0.f, a3 = 0.f;
        #pragma unroll
        for (int w = 0; w < 4; ++w) {
            const float* r = &MOb[(w*32 + q) * 36 + cseg * 4];
            a0 += r[0]; a1 += r[1]; a2 += r[2]; a3 += r[3];
        }
        uint2 pk;
        pk.x = pkh(a0 * invl, a1 * invl);
        pk.y = pkh(a2 * invl, a3 * invl);
        *(uint2*)&obf[(size_t)qg * DTOT + h * MIDC + cseg * 4] = pk;
    }
}

// ---------------- Kernel 3: output 1x1 conv via MFMA, LDS-staged Wo ----------
__global__ __launch_bounds__(256) void outproj_kernel(
    const f16* __restrict__ obf, const float* __restrict__ Wo,
    const float* __restrict__ bo, float* __restrict__ out)
{
    __shared__ f16  WoL[64][264];                // [d][cc] f16, pad 264 (33 KB)
    __shared__ float bol[64];

    const int tid = threadIdx.x;
    {
        int d = tid >> 2, part = tid & 3;
        const float* wr = &Wo[(size_t)d * DTOT];
        #pragma unroll
        for (int i = 0; i < 32; ++i) {
            int cc = part * 64 + i * 2;
            int h0 = cc >> 5, m0 = cc & 31;
            float w0 = wr[m0 * 8 + h0];
            float w1 = wr[(m0 + 1) * 8 + h0];
            *(uint_t*)&WoL[d][cc] = pkh(w0, w1);
        }
        if (tid < 64) bol[tid] = bo[tid];
    }
    __syncthreads();

    const int wave = tid >> 6, lane = tid & 63;
    const int qL = lane & 15, grp = lane >> 4;
    const int p = blockIdx.x * 64 + wave * 16 + qL;

    f32x4 acc[4];
    #pragma unroll
    for (int mt = 0; mt < 4; ++mt) acc[mt] = (f32x4){0,0,0,0};

    #pragma unroll
    for (int ks = 0; ks < 8; ++ks) {
        half8 bf = *(const half8*)&obf[(size_t)p * DTOT + ks * 32 + grp * 8];
        #pragma unroll
        for (int mt = 0; mt < 4; ++mt) {
            half8 af = *(const half8*)&WoL[mt * 16 + qL][ks * 32 + grp * 8];
            acc[mt] = __builtin_amdgcn_mfma_f32_16x16x32_f16(af, bf, acc[mt], 0, 0, 0);
        }
    }

    #pragma unroll
    for (int mt = 0; mt < 4; ++mt)
        #pragma unroll
        for (int r = 0; r < 4; ++r) {
            int d = mt * 16 + grp * 4 + r;
            out[(size_t)d * HW + p] = acc[mt][r] + bol[d];
        }
}

extern "C" void kernel_launch(void* const* d_in, const int* in_sizes, int n_in,
                              void* d_out, int out_size, void* d_ws, size_t ws_size,
                              hipStream_t stream)
{
    const float* x    = (const float*)d_in[0];
    const float* Wq   = (const float*)d_in[1];
    const float* bq   = (const float*)d_in[2];
    const float* Wk   = (const float*)d_in[3];
    const float* bk   = (const float*)d_in[4];
    const float* Wv   = (const float*)d_in[5];
    const float* bv   = (const float*)d_in[6];
    const float* Wo   = (const float*)d_in[7];
    const float* bo   = (const float*)d_in[8];
    const float* rowt = (const float*)d_in[9];
    const float* colt = (const float*)d_in[10];
    float* out = (float*)d_out;

    const size_t N = (size_t)DTOT * HW;
    f16* qh  = (f16*)d_ws;                       // [h][pos][32]
    f16* kh  = qh + N;
    f16* vh  = kh + N;                           // [h*32+m][pos]
    f16* obf = vh + N;                           // [pos][256] f16 normalized O

    qkv_fused_kernel<<<dim3(HW / 32, HEADS), 256, 0, stream>>>(
        x, Wq, bq, Wk, bk, Wv, bv, qh, kh, vh);
    attn_kernel<<<dim3(HW / QT, HEADS), 256, 0, stream>>>(
        qh, kh, vh, rowt, colt, obf);
    outproj_kernel<<<dim3(HW / 64), 256, 0, stream>>>(obf, Wo, bo, out);
}